// Round 10
// baseline (356.155 us; speedup 1.0000x reference)
//
#include <hip/hip_runtime.h>
#include <hip/hip_bf16.h>
#include <math.h>

// KoLeo loss: dist_i = sqrt(2 - 2*max_{j!=i} <fhat_i, fhat_j>); loss = -mean(log(dist+1e-8))
// Row-max-of-Gram via MX-scaled fp8 MFMA (16x16x128 f8f6f4, unit scales).
// R10: rectangular 128x256 block tile, 512 threads (2x4 grid of 64x64 wave tiles,
// same 64 AGPR + 64 VGPR budget — R8 proved zero register headroom at 4 waves/EU).
// Cuts staged-bytes/FLOP (5.7 vs 7.6 B/MF), DMA-instr/FLOP (-25%), barriers/FLOP
// (-50%) on the saturated LDS pipe. LDS 48KB -> 2 blocks/CU, 16 waves/CU (= R9).
// Coverage: tile (it,jt) computed iff jt >= it>>1; every pair (i<j) covered as
// (row=i,col=j); diag masked in BOTH row- and col-max; double-coverage idempotent
// under max; unwritten partial slots NaN-filled (fmaxf ignores NaN).
// Features pre-scaled x16 before e4m3 cast; raw dots carry x256, folded out in
// row_reduce (max is monotone).

#define N_ROWS 16384
#define DIM 1024     // elements per row == bytes per row in fp8
#define BTI 128      // block tile rows
#define BTJ 256      // block tile cols
#define BKB 128      // K bytes staged per iteration (= one K=128 MFMA)
#define NTI (N_ROWS / BTI)   // 128
#define NTJ (N_ROWS / BTJ)   // 64
#define NPLANES (NTJ + NTI)  // partial planes: 64 row-side + 128 col-side

typedef int   i32x4 __attribute__((ext_vector_type(4)));
typedef int   i32x8 __attribute__((ext_vector_type(8)));
typedef float f32x4 __attribute__((ext_vector_type(4)));

__device__ __forceinline__ void async16(const void* g, void* l) {
  __builtin_amdgcn_global_load_lds(
      (__attribute__((address_space(1))) const void*)g,
      (__attribute__((address_space(3))) void*)l, 16, 0, 0);
}

// ---------------------------------------------------------------- normalize
__global__ __launch_bounds__(256) void normalize_kernel(
    const float* __restrict__ in, unsigned int* __restrict__ outp) {
  const int row = blockIdx.x;
  const int t = threadIdx.x;  // 256 threads x 4 floats
  const float4 v = ((const float4*)(in + (size_t)row * DIM))[t];
  float ss = v.x * v.x + v.y * v.y + v.z * v.z + v.w * v.w;
#pragma unroll
  for (int s = 1; s < 64; s <<= 1) ss += __shfl_xor(ss, s, 64);
  __shared__ float wsum[4];
  const int wave = t >> 6, lane = t & 63;
  if (lane == 0) wsum[wave] = ss;
  __syncthreads();
  const float tot = wsum[0] + wsum[1] + wsum[2] + wsum[3];
  const float scale = 16.f / fmaxf(sqrtf(tot), 1e-12f);
  unsigned int p = __builtin_amdgcn_cvt_pk_fp8_f32(v.x * scale, v.y * scale, 0, false);
  p = __builtin_amdgcn_cvt_pk_fp8_f32(v.z * scale, v.w * scale, p, true);
  outp[(size_t)row * (DIM / 4) + t] = p;
}

// -------------------------------------------------- Gram row/col-max GEMM
__global__ __launch_bounds__(512, 4) void gemm_rowmax(
    const unsigned char* __restrict__ F, float* __restrict__ partial) {
  const int jt = blockIdx.x, it = blockIdx.y;
  if (jt < (it >> 1)) return;  // coverage rule: tile computed iff jt >= it>>1

  __shared__ __align__(16) unsigned char sA[BTI * BKB];  // 16KB
  __shared__ __align__(16) unsigned char sB[BTJ * BKB];  // 32KB (48KB total)

  const int ibase = it * BTI, jbase = jt * BTJ;
  const int tid = threadIdx.x;
  const int wave = tid >> 6, lane = tid & 63;
  const int wi = wave >> 2, wj = wave & 3;  // 2x4 wave grid, 64x64 each
  const int quad = lane >> 4, r16 = lane & 15;

  f32x4 acc[4][4] = {};  // [mi][ni], 16x16 tiles (AGPR-resident)

#pragma unroll 1
  for (int k0 = 0; k0 < DIM; k0 += BKB) {
    // Stage A (128 rows -> 1024 granules, 2 instrs/wave) and B (256 rows ->
    // 2048 granules, 4 instrs/wave); physical slot p holds granule p^(row&7).
#pragma unroll
    for (int a = 0; a < 2; ++a) {
      const int flatb = a * 512 + wave * 64;
      const int flat = flatb + lane;
      const int row = flat >> 3;
      const int off = (((flat & 7) ^ (row & 7)) << 4);
      async16(F + (size_t)(ibase + row) * DIM + k0 + off,
              (char*)sA + (size_t)flatb * 16);
    }
#pragma unroll
    for (int b = 0; b < 4; ++b) {
      const int flatb = b * 512 + wave * 64;
      const int flat = flatb + lane;
      const int row = flat >> 3;
      const int off = (((flat & 7) ^ (row & 7)) << 4);
      async16(F + (size_t)(jbase + row) * DIM + k0 + off,
              (char*)sB + (size_t)flatb * 16);
    }
    __syncthreads();  // vmcnt(0): staging visible

    // A-frags: lane holds 32 contiguous logical k-bytes (granules 2q,2q+1) of row R
    i32x8 afr[4];
#pragma unroll
    for (int mi = 0; mi < 4; ++mi) {
      const int R = wi * 64 + mi * 16 + r16;
      const unsigned char* base = sA + R * BKB;
      i32x4 lo = *(const i32x4*)(base + (((2 * quad) ^ (R & 7)) << 4));
      i32x4 hi = *(const i32x4*)(base + (((2 * quad + 1) ^ (R & 7)) << 4));
      afr[mi] = __builtin_shufflevector(lo, hi, 0, 1, 2, 3, 4, 5, 6, 7);
    }
#pragma unroll
    for (int ni = 0; ni < 4; ++ni) {
      const int R = wj * 64 + ni * 16 + r16;
      const unsigned char* base = sB + R * BKB;
      i32x4 lo = *(const i32x4*)(base + (((2 * quad) ^ (R & 7)) << 4));
      i32x4 hi = *(const i32x4*)(base + (((2 * quad + 1) ^ (R & 7)) << 4));
      i32x8 bfr = __builtin_shufflevector(lo, hi, 0, 1, 2, 3, 4, 5, 6, 7);
#pragma unroll
      for (int mi = 0; mi < 4; ++mi)
        acc[mi][ni] = __builtin_amdgcn_mfma_scale_f32_16x16x128_f8f6f4(
            afr[mi], bfr, acc[mi][ni], 0, 0,  // cbsz=0 (fp8), blgp=0 (fp8)
            0, 0x7F7F7F7F, 0, 0x7F7F7F7F);    // unit e8m0 scales
    }
    __syncthreads();  // close reads before restage
  }

  // Epilogue scratch aliases dead sA (all LDS reads closed by last barrier).
  float(*red)[4] = (float(*)[4])(&sA[0]);           // [BTI][4] row-max per wj
  float(*redc)[2] = (float(*)[2])(&sA[0] + 2048);   // [BTJ][2] col-max per wi

  // C/D layout (16x16): col = lane&15, row = quad*4 + reg.
  // Row-max, diag masked (raw x256 dots; scale folded out later).
#pragma unroll
  for (int mi = 0; mi < 4; ++mi) {
#pragma unroll
    for (int r = 0; r < 4; ++r) {
      const int rowg = ibase + wi * 64 + mi * 16 + quad * 4 + r;
      float m = -INFINITY;
#pragma unroll
      for (int ni = 0; ni < 4; ++ni) {
        const int colg = jbase + wj * 64 + ni * 16 + r16;
        const float v = acc[mi][ni][r];
        m = (rowg == colg) ? m : fmaxf(m, v);
      }
#pragma unroll
      for (int s = 1; s < 16; s <<= 1) m = fmaxf(m, __shfl_xor(m, s, 64));
      if (r16 == 0) red[wi * 64 + mi * 16 + quad * 4 + r][wj] = m;
    }
  }
  // Col-max, diag masked (diag can appear in tiles with jt == it>>1).
#pragma unroll
  for (int ni = 0; ni < 4; ++ni) {
    const int colg = jbase + wj * 64 + ni * 16 + r16;
    float m = -INFINITY;
#pragma unroll
    for (int mi = 0; mi < 4; ++mi)
#pragma unroll
      for (int r = 0; r < 4; ++r) {
        const int rowg = ibase + wi * 64 + mi * 16 + quad * 4 + r;
        const float v = acc[mi][ni][r];
        m = (rowg == colg) ? m : fmaxf(m, v);
      }
    m = fmaxf(m, __shfl_xor(m, 16, 64));  // reduce across quads
    m = fmaxf(m, __shfl_xor(m, 32, 64));
    if (quad == 0) redc[wj * 64 + ni * 16 + r16][wi] = m;
  }
  __syncthreads();
  if (tid < BTI) {
    const float m = fmaxf(fmaxf(red[tid][0], red[tid][1]),
                          fmaxf(red[tid][2], red[tid][3]));
    partial[(size_t)jt * N_ROWS + ibase + tid] = m;  // row-side plane jt
  } else if (tid < BTI + BTJ) {
    const int c = tid - BTI;
    partial[(size_t)(NTJ + it) * N_ROWS + jbase + c] =
        fmaxf(redc[c][0], redc[c][1]);               // col-side plane 64+it
  }
}

// ------------------------------------------------------------- reductions
__global__ __launch_bounds__(256) void row_reduce(
    const float* __restrict__ partial, float* __restrict__ blocksum) {
  const int r = blockIdx.x * 256 + threadIdx.x;
  float m = -INFINITY;
  for (int p = 0; p < NPLANES; ++p)
    m = fmaxf(m, partial[(size_t)p * N_ROWS + r]);  // NaN (unwritten) ignored
  // raw dot carries x256 (features scaled x16): 2 - 2*(m/256) = 2 - m/128
  const float d2 = fmaxf(2.f - m * (1.f / 128.f), 0.f);
  float term = logf(sqrtf(d2) + 1e-8f);
#pragma unroll
  for (int s = 1; s < 64; s <<= 1) term += __shfl_xor(term, s, 64);
  __shared__ float wsum[4];
  const int wave = threadIdx.x >> 6, lane = threadIdx.x & 63;
  if (lane == 0) wsum[wave] = term;
  __syncthreads();
  if (threadIdx.x == 0)
    blocksum[blockIdx.x] = wsum[0] + wsum[1] + wsum[2] + wsum[3];
}

__global__ void finalize(const float* __restrict__ blocksum,
                         float* __restrict__ out) {
  float v = blocksum[threadIdx.x];
#pragma unroll
  for (int s = 1; s < 64; s <<= 1) v += __shfl_xor(v, s, 64);
  if (threadIdx.x == 0) out[0] = -v / (float)N_ROWS;
}

// ---------------------------------------------------------------- launcher
extern "C" void kernel_launch(void* const* d_in, const int* in_sizes, int n_in,
                              void* d_out, int out_size, void* d_ws, size_t ws_size,
                              hipStream_t stream) {
  const float* feats = (const float*)d_in[0];
  float* out = (float*)d_out;
  char* ws = (char*)d_ws;

  // ws: [0,16MB) fp8 features; then partial [192][16384] f32 (12MB); then sums.
  unsigned char* f8 = (unsigned char*)ws;
  float* partial = (float*)(ws + (size_t)N_ROWS * DIM);
  float* blocksum =
      (float*)(ws + (size_t)N_ROWS * DIM + (size_t)NPLANES * N_ROWS * 4);

  normalize_kernel<<<N_ROWS, 256, 0, stream>>>(feats, (unsigned int*)f8);
  // NaN-fill partial so planes not covered by the jt>=it>>1 rule are ignored
  // by fmaxf in row_reduce (0xFF bytes = NaN).
  hipMemsetAsync(partial, 0xFF, (size_t)NPLANES * N_ROWS * 4, stream);
  gemm_rowmax<<<dim3(NTJ, NTI), 512, 0, stream>>>(f8, partial);
  row_reduce<<<N_ROWS / 256, 256, 0, stream>>>(partial, blocksum);
  finalize<<<1, 64, 0, stream>>>(blocksum, out);
}

// Round 11
// 281.741 us; speedup vs baseline: 1.2641x; 1.2641x over previous
//
#include <hip/hip_runtime.h>
#include <hip/hip_bf16.h>
#include <math.h>

// KoLeo loss: dist_i = sqrt(2 - 2*max_{j!=i} <fhat_i, fhat_j>); loss = -mean(log(dist+1e-8))
// Row-max-of-Gram via MX-scaled fp8 MFMA (16x16x128 f8f6f4, unit scales, 4x4
// tiles/wave, single-buffered LDS, global_load_lds staging). FINAL = R9 verbatim:
// best measured configuration (total 282 us, gemm 192 us, MfmaUtil 31%, Occ 42%).
// Measured design-space brackets: LDS dbuf (R6, -14%), register prefetch (R8,
// spills at the 64 AGPR + 64 VGPR = 128 unified-file cap, -3x), 128x256 tile
// (R10, -17%), (256,4) occupancy + triangular 1D launch (R7/R9, the wins).
// Features pre-scaled x16 before e4m3 cast; raw dots carry x256, folded out in
// row_reduce (max is monotone). Each tile yields row-max AND col-max.

#define N_ROWS 16384
#define DIM 1024     // elements per row == bytes per row in fp8
#define BT 128       // Gram tile edge
#define BKB 128      // K bytes staged per iteration (= one K=128 MFMA)
#define NT (N_ROWS / BT)

typedef int   i32x4 __attribute__((ext_vector_type(4)));
typedef int   i32x8 __attribute__((ext_vector_type(8)));
typedef float f32x4 __attribute__((ext_vector_type(4)));

__device__ __forceinline__ void async16(const void* g, void* l) {
  __builtin_amdgcn_global_load_lds(
      (__attribute__((address_space(1))) const void*)g,
      (__attribute__((address_space(3))) void*)l, 16, 0, 0);
}

// ---------------------------------------------------------------- normalize
__global__ __launch_bounds__(256) void normalize_kernel(
    const float* __restrict__ in, unsigned int* __restrict__ outp) {
  const int row = blockIdx.x;
  const int t = threadIdx.x;  // 256 threads x 4 floats
  const float4 v = ((const float4*)(in + (size_t)row * DIM))[t];
  float ss = v.x * v.x + v.y * v.y + v.z * v.z + v.w * v.w;
#pragma unroll
  for (int s = 1; s < 64; s <<= 1) ss += __shfl_xor(ss, s, 64);
  __shared__ float wsum[4];
  const int wave = t >> 6, lane = t & 63;
  if (lane == 0) wsum[wave] = ss;
  __syncthreads();
  const float tot = wsum[0] + wsum[1] + wsum[2] + wsum[3];
  const float scale = 16.f / fmaxf(sqrtf(tot), 1e-12f);
  unsigned int p = __builtin_amdgcn_cvt_pk_fp8_f32(v.x * scale, v.y * scale, 0, false);
  p = __builtin_amdgcn_cvt_pk_fp8_f32(v.z * scale, v.w * scale, p, true);
  outp[(size_t)row * (DIM / 4) + t] = p;
}

// -------------------------------------------------- Gram row/col-max GEMM
__global__ __launch_bounds__(256, 4) void gemm_rowmax(
    const unsigned char* __restrict__ F, float* __restrict__ partial) {
  // triangular decode: bid -> (it, jt), it <= jt (verified exact in R3)
  const int bid = blockIdx.x;
  double disc = (double)(2 * NT + 1) * (2 * NT + 1) - 8.0 * (double)bid;
  int it = (int)(((2 * NT + 1) - sqrt(disc)) * 0.5);
  if (it > NT - 1) it = NT - 1;
  while (it > 0 && it * NT - it * (it - 1) / 2 > bid) --it;
  while ((it + 1) * NT - (it + 1) * it / 2 <= bid) ++it;
  const int jt = it + (bid - (it * NT - it * (it - 1) / 2));

  __shared__ __align__(16) unsigned char sA[BT * BKB];  // [row][k-byte, swizzled]
  __shared__ __align__(16) unsigned char sB[BT * BKB];
  __shared__ float red[BT][2];
  __shared__ float redc[BT][2];

  const int ibase = it * BT, jbase = jt * BT;
  const int tid = threadIdx.x;
  const int wave = tid >> 6, lane = tid & 63;
  const int wi = wave >> 1, wj = wave & 1;  // 2x2 wave grid, 64x64 each
  const int quad = lane >> 4, r16 = lane & 15;

  f32x4 acc[4][4] = {};  // [mi][ni], 16x16 tiles (AGPR-resident)

#pragma unroll 1
  for (int k0 = 0; k0 < DIM; k0 += BKB) {
    // stage A rows [ibase,+128) and B rows [jbase,+128): 8 granules/row,
    // physical slot p holds logical granule p ^ (row&7)
#pragma unroll
    for (int q = 0; q < 4; ++q) {
      const int flatb = q * 256 + wave * 64;  // wave-uniform granule base
      const int flat = flatb + lane;          // physical granule = row*8 + k16
      const int row = flat >> 3;
      const int k16 = flat & 7;
      const int off = ((k16 ^ (row & 7)) << 4);  // logical granule byte offset
      async16(F + (size_t)(ibase + row) * DIM + k0 + off,
              (char*)sA + (size_t)flatb * 16);
      async16(F + (size_t)(jbase + row) * DIM + k0 + off,
              (char*)sB + (size_t)flatb * 16);
    }
    __syncthreads();
    // A-frags: lane holds 32 contiguous k-bytes (granules 2q, 2q+1) of row R
    i32x8 afr[4];
#pragma unroll
    for (int mi = 0; mi < 4; ++mi) {
      const int R = wi * 64 + mi * 16 + r16;
      const unsigned char* base = sA + R * BKB;
      i32x4 lo = *(const i32x4*)(base + (((2 * quad) ^ (R & 7)) << 4));
      i32x4 hi = *(const i32x4*)(base + (((2 * quad + 1) ^ (R & 7)) << 4));
      afr[mi] = __builtin_shufflevector(lo, hi, 0, 1, 2, 3, 4, 5, 6, 7);
    }
#pragma unroll
    for (int ni = 0; ni < 4; ++ni) {
      const int R = wj * 64 + ni * 16 + r16;
      const unsigned char* base = sB + R * BKB;
      i32x4 lo = *(const i32x4*)(base + (((2 * quad) ^ (R & 7)) << 4));
      i32x4 hi = *(const i32x4*)(base + (((2 * quad + 1) ^ (R & 7)) << 4));
      i32x8 bfr = __builtin_shufflevector(lo, hi, 0, 1, 2, 3, 4, 5, 6, 7);
#pragma unroll
      for (int mi = 0; mi < 4; ++mi)
        acc[mi][ni] = __builtin_amdgcn_mfma_scale_f32_16x16x128_f8f6f4(
            afr[mi], bfr, acc[mi][ni], 0, 0,  // cbsz=0 (fp8), blgp=0 (fp8)
            0, 0x7F7F7F7F, 0, 0x7F7F7F7F);    // unit e8m0 scales
    }
    __syncthreads();
  }

  // C/D layout (16x16): col = lane&15, row = quad*4 + reg.
  // Row-max with diagonal mask (raw x256 dots; scale folded out later).
#pragma unroll
  for (int mi = 0; mi < 4; ++mi) {
#pragma unroll
    for (int r = 0; r < 4; ++r) {
      const int rowg = ibase + wi * 64 + mi * 16 + quad * 4 + r;
      float m = -INFINITY;
#pragma unroll
      for (int ni = 0; ni < 4; ++ni) {
        const int colg = jbase + wj * 64 + ni * 16 + r16;
        const float v = acc[mi][ni][r];
        m = (rowg == colg) ? m : fmaxf(m, v);
      }
#pragma unroll
      for (int s = 1; s < 16; s <<= 1) m = fmaxf(m, __shfl_xor(m, s, 64));
      if (r16 == 0) red[wi * 64 + mi * 16 + quad * 4 + r][wj] = m;
    }
  }
  // Col-max (off-diagonal tiles: no diag elements present)
  if (it != jt) {
#pragma unroll
    for (int ni = 0; ni < 4; ++ni) {
      float m = -INFINITY;
#pragma unroll
      for (int mi = 0; mi < 4; ++mi)
#pragma unroll
        for (int r = 0; r < 4; ++r) m = fmaxf(m, acc[mi][ni][r]);
      m = fmaxf(m, __shfl_xor(m, 16, 64));  // reduce across quads
      m = fmaxf(m, __shfl_xor(m, 32, 64));
      if (quad == 0) redc[wj * 64 + ni * 16 + r16][wi] = m;
    }
  }
  __syncthreads();
  if (tid < BT) {
    partial[(size_t)jt * N_ROWS + ibase + tid] = fmaxf(red[tid][0], red[tid][1]);
  } else if (it != jt) {
    const int c = tid - BT;
    partial[(size_t)it * N_ROWS + jbase + c] = fmaxf(redc[c][0], redc[c][1]);
  }
}

// ------------------------------------------------------------- reductions
__global__ __launch_bounds__(256) void row_reduce(
    const float* __restrict__ partial, float* __restrict__ blocksum) {
  const int r = blockIdx.x * 256 + threadIdx.x;
  float m = -INFINITY;
  for (int p = 0; p < N_ROWS / BT; ++p)
    m = fmaxf(m, partial[(size_t)p * N_ROWS + r]);
  // raw dot carries x256 (features scaled x16): 2 - 2*(m/256) = 2 - m/128
  const float d2 = fmaxf(2.f - m * (1.f / 128.f), 0.f);
  float term = logf(sqrtf(d2) + 1e-8f);
#pragma unroll
  for (int s = 1; s < 64; s <<= 1) term += __shfl_xor(term, s, 64);
  __shared__ float wsum[4];
  const int wave = threadIdx.x >> 6, lane = threadIdx.x & 63;
  if (lane == 0) wsum[wave] = term;
  __syncthreads();
  if (threadIdx.x == 0)
    blocksum[blockIdx.x] = wsum[0] + wsum[1] + wsum[2] + wsum[3];
}

__global__ void finalize(const float* __restrict__ blocksum,
                         float* __restrict__ out) {
  float v = blocksum[threadIdx.x];
#pragma unroll
  for (int s = 1; s < 64; s <<= 1) v += __shfl_xor(v, s, 64);
  if (threadIdx.x == 0) out[0] = -v / (float)N_ROWS;
}

// ---------------------------------------------------------------- launcher
extern "C" void kernel_launch(void* const* d_in, const int* in_sizes, int n_in,
                              void* d_out, int out_size, void* d_ws, size_t ws_size,
                              hipStream_t stream) {
  const float* feats = (const float*)d_in[0];
  float* out = (float*)d_out;
  char* ws = (char*)d_ws;

  // ws: [0,16MB) fp8 features; [16MB,24MB) partial [128][16384] f32; then sums.
  unsigned char* f8 = (unsigned char*)ws;
  float* partial = (float*)(ws + (size_t)N_ROWS * DIM);
  float* blocksum =
      (float*)(ws + (size_t)N_ROWS * DIM + (size_t)NT * N_ROWS * 4);

  normalize_kernel<<<N_ROWS, 256, 0, stream>>>(feats, (unsigned int*)f8);
  gemm_rowmax<<<NT * (NT + 1) / 2, 256, 0, stream>>>(f8, partial);
  row_reduce<<<N_ROWS / 256, 256, 0, stream>>>(partial, blocksum);
  finalize<<<1, 64, 0, stream>>>(blocksum, out);
}